// Round 1
// baseline (1998.469 us; speedup 1.0000x reference)
//
#include <hip/hip_runtime.h>
#include <hip/hip_bf16.h>

// Problem constants (B,T,E,H,D) = (2,2048,1024,16,64)
constexpr int B = 2, T = 2048, E = 1024, H = 16, D = 64;
constexpr int ROWS = B * T;                     // 4096
constexpr float INV_SCALE = 0.022097086912079608f;  // 1/sqrt(2048)
constexpr size_t QSZ = (size_t)H * ROWS * D;    // 4,194,304 floats per q/k/v buffer
constexpr float NEG_BIG = -1e30f;

// ---------------------------------------------------------------------------
// Kernel 1: QKV projection.  For each (which,h): C[4096,64] = X[4096,1024] @ W[h][1024,64]
// grid = (64 row-tiles, 3*H);  block = 256 (16x16 threads, 4x4 register tile each)
// Strided ownership: thread (ty,tx) owns rows {ty+16i}, cols {tx+16j}  -> conflict-free LDS.
// ---------------------------------------------------------------------------
__global__ __launch_bounds__(256) void qkv_kernel(const float* __restrict__ x,
                                                  const float* __restrict__ Wq,
                                                  const float* __restrict__ Wk,
                                                  const float* __restrict__ Wv,
                                                  float* __restrict__ q,
                                                  float* __restrict__ k,
                                                  float* __restrict__ v) {
    __shared__ float As[64][33];   // x tile: rows x e   (pad 33 -> bank-free col reads)
    __shared__ float Ws[32][65];   // W tile: e x i      (pad 65 -> bank-free row reads)

    const int tid = threadIdx.x;
    const int rt = blockIdx.x;            // row tile
    const int wz = blockIdx.y;            // which*H + h
    const int which = wz >> 4;            // 0=q, 1=k, 2=v   (H==16)
    const int h = wz & 15;
    const float* __restrict__ W = (which == 0) ? Wq : ((which == 1) ? Wk : Wv);
    float* __restrict__ out = (which == 0) ? q : ((which == 1) ? k : v);

    const int r0 = rt * 64;
    const int ty = tid >> 4, tx = tid & 15;

    float acc[4][4] = {};

    for (int e0 = 0; e0 < E; e0 += 32) {
        __syncthreads();
        // stage A (64 rows x 32 e), coalesced float4
        #pragma unroll
        for (int rep = 0; rep < 2; ++rep) {
            const int f = tid + rep * 256;        // float4 index in [0,512)
            const int row = f >> 3, c4 = (f & 7) * 4;
            const float4 val = *reinterpret_cast<const float4*>(
                &x[(size_t)(r0 + row) * E + e0 + c4]);
            As[row][c4 + 0] = val.x; As[row][c4 + 1] = val.y;
            As[row][c4 + 2] = val.z; As[row][c4 + 3] = val.w;
        }
        // stage W (32 e x 64 i), coalesced float4
        #pragma unroll
        for (int rep = 0; rep < 2; ++rep) {
            const int f = tid + rep * 256;
            const int e = f >> 4, i4 = (f & 15) * 4;
            const float4 val = *reinterpret_cast<const float4*>(
                &W[(size_t)h * E * D + (size_t)(e0 + e) * D + i4]);
            Ws[e][i4 + 0] = val.x; Ws[e][i4 + 1] = val.y;
            Ws[e][i4 + 2] = val.z; Ws[e][i4 + 3] = val.w;
        }
        __syncthreads();

        #pragma unroll
        for (int kk = 0; kk < 32; ++kk) {
            float a[4], w[4];
            #pragma unroll
            for (int i = 0; i < 4; ++i) a[i] = As[ty + 16 * i][kk];
            #pragma unroll
            for (int j = 0; j < 4; ++j) w[j] = Ws[kk][tx + 16 * j];
            #pragma unroll
            for (int i = 0; i < 4; ++i)
                #pragma unroll
                for (int j = 0; j < 4; ++j)
                    acc[i][j] += a[i] * w[j];
        }
    }

    const float s = (which == 0) ? INV_SCALE : 1.0f;   // fold 1/sqrt(T) into Q
    #pragma unroll
    for (int i = 0; i < 4; ++i) {
        const int row = r0 + ty + 16 * i;
        #pragma unroll
        for (int j = 0; j < 4; ++j) {
            out[((size_t)h * ROWS + row) * D + tx + 16 * j] = acc[i][j] * s;
        }
    }
}

// ---------------------------------------------------------------------------
// Kernel 2: flash attention, fp32.  grid = (32 q-tiles, H*B);  block = 256.
// Per block: 64 q-rows; iterate causal K/V tiles with online softmax.
// P is written into the K buffer (keeps static LDS < 64KB).
// ---------------------------------------------------------------------------
__global__ __launch_bounds__(256) void attn_kernel(const float* __restrict__ q,
                                                   const float* __restrict__ k,
                                                   const float* __restrict__ v,
                                                   float* __restrict__ att) {
    __shared__ float Qs[64][65];
    __shared__ float KPs[64][65];   // K tile, then reused for P
    __shared__ float Vs[64][65];

    const int tid = threadIdx.x;
    const int qt = blockIdx.x;          // 0..31
    const int hb = blockIdx.y;          // h*B + b
    const int h = hb >> 1, b = hb & 1;
    const size_t base = (size_t)hb * T * D;   // start of this (h,b)'s rows
    const int ty = tid >> 4, tx = tid & 15;

    // stage Q tile (already scaled by 1/sqrt(T))
    #pragma unroll
    for (int rep = 0; rep < 4; ++rep) {
        const int f = tid + rep * 256;        // float4 index in [0,1024)
        const int row = f >> 4, c4 = (f & 15) * 4;
        const float4 val = *reinterpret_cast<const float4*>(
            &q[base + (size_t)(qt * 64 + row) * D + c4]);
        Qs[row][c4 + 0] = val.x; Qs[row][c4 + 1] = val.y;
        Qs[row][c4 + 2] = val.z; Qs[row][c4 + 3] = val.w;
    }

    float O[4][4] = {};
    float m[4], l[4];
    #pragma unroll
    for (int i = 0; i < 4; ++i) { m[i] = NEG_BIG; l[i] = 0.0f; }

    for (int kt = 0; kt <= qt; ++kt) {
        __syncthreads();   // prior PV reads of KPs/Vs done before overwrite
        #pragma unroll
        for (int rep = 0; rep < 4; ++rep) {
            const int f = tid + rep * 256;
            const int row = f >> 4, c4 = (f & 15) * 4;
            const size_t g = base + (size_t)(kt * 64 + row) * D + c4;
            const float4 kv = *reinterpret_cast<const float4*>(&k[g]);
            KPs[row][c4 + 0] = kv.x; KPs[row][c4 + 1] = kv.y;
            KPs[row][c4 + 2] = kv.z; KPs[row][c4 + 3] = kv.w;
            const float4 vv = *reinterpret_cast<const float4*>(&v[g]);
            Vs[row][c4 + 0] = vv.x; Vs[row][c4 + 1] = vv.y;
            Vs[row][c4 + 2] = vv.z; Vs[row][c4 + 3] = vv.w;
        }
        __syncthreads();

        // S = Q * K^T  (4x4 per thread)
        float S[4][4] = {};
        #pragma unroll
        for (int d = 0; d < 64; ++d) {
            float qq[4], kk2[4];
            #pragma unroll
            for (int i = 0; i < 4; ++i) qq[i] = Qs[ty + 16 * i][d];
            #pragma unroll
            for (int j = 0; j < 4; ++j) kk2[j] = KPs[tx + 16 * j][d];
            #pragma unroll
            for (int i = 0; i < 4; ++i)
                #pragma unroll
                for (int j = 0; j < 4; ++j)
                    S[i][j] += qq[i] * kk2[j];
        }
        if (kt == qt) {   // causal mask on the diagonal tile
            #pragma unroll
            for (int i = 0; i < 4; ++i)
                #pragma unroll
                for (int j = 0; j < 4; ++j)
                    if (tx + 16 * j > ty + 16 * i) S[i][j] = NEG_BIG;
        }

        // online softmax stats (row groups = 16 consecutive lanes)
        float P[4][4];
        #pragma unroll
        for (int i = 0; i < 4; ++i) {
            float rowmax = S[i][0];
            #pragma unroll
            for (int j = 1; j < 4; ++j) rowmax = fmaxf(rowmax, S[i][j]);
            #pragma unroll
            for (int w = 1; w < 16; w <<= 1)
                rowmax = fmaxf(rowmax, __shfl_xor(rowmax, w));
            const float m_new = fmaxf(m[i], rowmax);
            const float fac = __expf(m[i] - m_new);
            float rs = 0.0f;
            #pragma unroll
            for (int j = 0; j < 4; ++j) {
                P[i][j] = __expf(S[i][j] - m_new);
                rs += P[i][j];
            }
            #pragma unroll
            for (int w = 1; w < 16; w <<= 1)
                rs += __shfl_xor(rs, w);
            l[i] = l[i] * fac + rs;
            m[i] = m_new;
            #pragma unroll
            for (int j = 0; j < 4; ++j) O[i][j] *= fac;
        }

        __syncthreads();   // everyone done reading K before P overwrites it
        #pragma unroll
        for (int i = 0; i < 4; ++i)
            #pragma unroll
            for (int j = 0; j < 4; ++j)
                KPs[ty + 16 * i][tx + 16 * j] = P[i][j];
        __syncthreads();

        // O += P * V
        #pragma unroll
        for (int c = 0; c < 64; ++c) {
            float pp[4], vv[4];
            #pragma unroll
            for (int i = 0; i < 4; ++i) pp[i] = KPs[ty + 16 * i][c];
            #pragma unroll
            for (int j = 0; j < 4; ++j) vv[j] = Vs[c][tx + 16 * j];
            #pragma unroll
            for (int i = 0; i < 4; ++i)
                #pragma unroll
                for (int j = 0; j < 4; ++j)
                    O[i][j] += pp[i] * vv[j];
        }
    }

    // epilogue: normalize, write att as [B][T][H*D]
    #pragma unroll
    for (int i = 0; i < 4; ++i) {
        const float inv = 1.0f / l[i];
        const int t = qt * 64 + ty + 16 * i;
        #pragma unroll
        for (int j = 0; j < 4; ++j) {
            att[((size_t)(b * T + t)) * E + h * D + tx + 16 * j] = O[i][j] * inv;
        }
    }
}

// ---------------------------------------------------------------------------
// Kernel 3: output projection.  out[m,o] = sum_i att[m,i] * Wo[o,i]
// Both operands row-contiguous along reduction -> identical tile layouts.
// grid = (64 m-tiles, 16 o-tiles);  block = 256.
// ---------------------------------------------------------------------------
__global__ __launch_bounds__(256) void outproj_kernel(const float* __restrict__ a,
                                                      const float* __restrict__ Wo,
                                                      float* __restrict__ out) {
    __shared__ float As[64][33];
    __shared__ float Ws[64][33];

    const int tid = threadIdx.x;
    const int mt = blockIdx.x;       // 0..63
    const int ot = blockIdx.y;       // 0..15
    const int ty = tid >> 4, tx = tid & 15;

    float acc[4][4] = {};

    for (int i0 = 0; i0 < E; i0 += 32) {
        __syncthreads();
        #pragma unroll
        for (int rep = 0; rep < 2; ++rep) {
            const int f = tid + rep * 256;
            const int row = f >> 3, c4 = (f & 7) * 4;
            const float4 av = *reinterpret_cast<const float4*>(
                &a[(size_t)(mt * 64 + row) * E + i0 + c4]);
            As[row][c4 + 0] = av.x; As[row][c4 + 1] = av.y;
            As[row][c4 + 2] = av.z; As[row][c4 + 3] = av.w;
            const float4 wv = *reinterpret_cast<const float4*>(
                &Wo[(size_t)(ot * 64 + row) * E + i0 + c4]);
            Ws[row][c4 + 0] = wv.x; Ws[row][c4 + 1] = wv.y;
            Ws[row][c4 + 2] = wv.z; Ws[row][c4 + 3] = wv.w;
        }
        __syncthreads();

        #pragma unroll
        for (int kk = 0; kk < 32; ++kk) {
            float aa[4], ww[4];
            #pragma unroll
            for (int i = 0; i < 4; ++i) aa[i] = As[ty + 16 * i][kk];
            #pragma unroll
            for (int j = 0; j < 4; ++j) ww[j] = Ws[tx + 16 * j][kk];
            #pragma unroll
            for (int i = 0; i < 4; ++i)
                #pragma unroll
                for (int j = 0; j < 4; ++j)
                    acc[i][j] += aa[i] * ww[j];
        }
    }

    #pragma unroll
    for (int i = 0; i < 4; ++i) {
        const int row = mt * 64 + ty + 16 * i;
        #pragma unroll
        for (int j = 0; j < 4; ++j) {
            out[(size_t)row * E + ot * 64 + tx + 16 * j] = acc[i][j];
        }
    }
}

// ---------------------------------------------------------------------------
extern "C" void kernel_launch(void* const* d_in, const int* in_sizes, int n_in,
                              void* d_out, int out_size, void* d_ws, size_t ws_size,
                              hipStream_t stream) {
    const float* x  = (const float*)d_in[0];
    // d_in[1] is the boolean causal mask -- deterministic, applied analytically.
    const float* Wq = (const float*)d_in[2];
    const float* Wk = (const float*)d_in[3];
    const float* Wv = (const float*)d_in[4];
    const float* Wo = (const float*)d_in[5];
    float* ws = (float*)d_ws;
    float* q   = ws;                 // [H][B*T][D]
    float* k   = ws + QSZ;
    float* v   = ws + 2 * QSZ;
    float* att = ws + 3 * QSZ;       // [B*T][E]
    float* out = (float*)d_out;

    qkv_kernel<<<dim3(64, 48), 256, 0, stream>>>(x, Wq, Wk, Wv, q, k, v);
    attn_kernel<<<dim3(32, 32), 256, 0, stream>>>(q, k, v, att);
    outproj_kernel<<<dim3(64, 16), 256, 0, stream>>>(att, Wo, out);
}

// Round 2
// 272.023 us; speedup vs baseline: 7.3467x; 7.3467x over previous
//
#include <hip/hip_runtime.h>
#include <stdint.h>

// (B,T,E,H,D) = (2,2048,1024,16,64)
constexpr float INV_SCALE = 0.022097086912079608f;  // 1/sqrt(2048)

typedef __attribute__((ext_vector_type(8))) short bfrag;          // 8 bf16 (4 VGPR) MFMA frag
typedef __attribute__((ext_vector_type(4))) float facc;           // 4 f32 MFMA acc
typedef __attribute__((ext_vector_type(4))) unsigned short us4;   // 4 bf16 = 8B

#define MFMA(a, b, c) __builtin_amdgcn_mfma_f32_16x16x32_bf16((a), (b), (c), 0, 0, 0)

__device__ __forceinline__ unsigned short f2bh(float f) {        // f32 -> bf16 RNE
    union { float f; unsigned int u; } cv; cv.f = f;
    unsigned int u = cv.u;
    u += 0x7FFFu + ((u >> 16) & 1u);
    return (unsigned short)(u >> 16);
}
__device__ __forceinline__ float bh2f(unsigned short h) {
    union { unsigned int u; float f; } cv; cv.u = ((unsigned int)h) << 16;
    return cv.f;
}
__device__ __forceinline__ void gl_lds16(const unsigned short* g, unsigned short* lds) {
    // async 16B/lane global->LDS; dst is wave-uniform base, lane i lands at dst+16*i
    __builtin_amdgcn_global_load_lds(
        (const __attribute__((address_space(1))) unsigned int*)g,
        (__attribute__((address_space(3))) unsigned int*)lds, 16, 0, 0);
}

// ---------------------------------------------------------------------------
// prep_w: per head, transpose W[h][1024 e][64 i] -> WT[h*64+i][1024 e] with
// hi/lo bf16 split for Wq/Wk (Q/K path needs ~fp32 logits), hi-only for Wv.
// grid (16 etiles, 16 heads, 3), block 256.
// ---------------------------------------------------------------------------
__global__ __launch_bounds__(256) void prep_w(
    const float* __restrict__ Wq, const float* __restrict__ Wk, const float* __restrict__ Wv,
    unsigned short* __restrict__ WqTh, unsigned short* __restrict__ WqTl,
    unsigned short* __restrict__ WkTh, unsigned short* __restrict__ WkTl,
    unsigned short* __restrict__ WvT)
{
    __shared__ float tile[64][65];
    const int tid = threadIdx.x;
    const int et = blockIdx.x, h = blockIdx.y, m = blockIdx.z;
    const float* W = (m == 0) ? Wq : (m == 1) ? Wk : Wv;
    #pragma unroll
    for (int rep = 0; rep < 4; ++rep) {
        int idx = rep * 256 + tid;            // f4 idx over [64e][16 i4]
        int e = idx >> 4, i4 = (idx & 15) * 4;
        facc v = *(const facc*)&W[(size_t)h * 65536 + (size_t)(et * 64 + e) * 64 + i4];
        tile[e][i4] = v.x; tile[e][i4 + 1] = v.y; tile[e][i4 + 2] = v.z; tile[e][i4 + 3] = v.w;
    }
    __syncthreads();
    unsigned short* Oh = (m == 0) ? WqTh : (m == 1) ? WkTh : WvT;
    unsigned short* Ol = (m == 0) ? WqTl : WkTl;   // unused when m==2
    #pragma unroll
    for (int rep = 0; rep < 4; ++rep) {
        int idx = rep * 256 + tid;            // [64 i][16 e4]
        int i = idx >> 4, e4 = (idx & 15) * 4;
        us4 hv, lv;
        #pragma unroll
        for (int j = 0; j < 4; ++j) {
            float f = tile[e4 + j][i];
            unsigned short hb = f2bh(f);
            hv[j] = hb;
            lv[j] = f2bh(f - bh2f(hb));
        }
        size_t o = (size_t)(h * 64 + i) * 1024 + et * 64 + e4;
        *(us4*)&Oh[o] = hv;
        if (m < 2) *(us4*)&Ol[o] = lv;
    }
}

// Wo [1024 o][1024 i] fp32 -> bf16 (already B^T layout for out = att @ Wo^T)
__global__ __launch_bounds__(256) void wo_conv(const float* __restrict__ Wo,
                                               unsigned short* __restrict__ WoB) {
    int idx = blockIdx.x * 256 + threadIdx.x;   // f4 index, 262144 total
    facc v = *(const facc*)&Wo[(size_t)idx * 4];
    us4 o;
    #pragma unroll
    for (int j = 0; j < 4; ++j) o[j] = f2bh(v[j]);
    *(us4*)&WoB[(size_t)idx * 4] = o;
}

// ---------------------------------------------------------------------------
// qkv_gemm: C[4096,1024] = X @ W  per which in {q,k,v}.  128x128 tile, BK=32,
// 4 waves each 64x64 (4x4 frags).  A staged from fp32 with in-kernel hi/lo
// split; B via global_load_lds from pre-split planes.  q/k: 3-term split MFMA.
// Epilogue: q,k -> hi/lo planes (q pre-scaled); v -> transposed vT[hd][t].
// grid (32, 8, 3), block 256.
// ---------------------------------------------------------------------------
__global__ __launch_bounds__(256) void qkv_gemm(
    const float* __restrict__ x,
    const unsigned short* __restrict__ WqTh, const unsigned short* __restrict__ WqTl,
    const unsigned short* __restrict__ WkTh, const unsigned short* __restrict__ WkTl,
    const unsigned short* __restrict__ WvT,
    unsigned short* __restrict__ qh, unsigned short* __restrict__ ql,
    unsigned short* __restrict__ kh, unsigned short* __restrict__ kl,
    unsigned short* __restrict__ vT)
{
    __shared__ unsigned short Ah[128 * 32], Al[128 * 32], Bh[128 * 32], Bl[128 * 32];
    const int tid = threadIdx.x;
    const int w = tid >> 6, l = tid & 63;
    const int wm = w >> 1, wn = w & 1;
    const int rt = blockIdx.x, ct = blockIdx.y, which = blockIdx.z;
    const bool split = (which < 2);
    const unsigned short* Bhg = (which == 0) ? WqTh : (which == 1) ? WkTh : WvT;
    const unsigned short* Blg = (which == 0) ? WqTl : WkTl;

    facc acc[4][4];
    #pragma unroll
    for (int i = 0; i < 4; ++i)
        #pragma unroll
        for (int j = 0; j < 4; ++j) acc[i][j] = (facc)(0.0f);

    for (int e0 = 0; e0 < 1024; e0 += 32) {
        __syncthreads();
        // stage A: 128x32 fp32 -> bf16 hi/lo
        #pragma unroll
        for (int rep = 0; rep < 4; ++rep) {
            int idx = rep * 256 + tid;          // f4 idx, 1024 total
            int row = idx >> 3, c4 = (idx & 7) * 4;
            facc xv = *(const facc*)&x[(size_t)(rt * 128 + row) * 1024 + e0 + c4];
            us4 hv, lv;
            #pragma unroll
            for (int j = 0; j < 4; ++j) {
                float f = xv[j];
                unsigned short hb = f2bh(f);
                hv[j] = hb;
                lv[j] = f2bh(f - bh2f(hb));
            }
            *(us4*)&Ah[row * 32 + c4] = hv;
            if (split) *(us4*)&Al[row * 32 + c4] = lv;
        }
        // stage B (8KB/plane, 8 x 1KB wave-slices)
        #pragma unroll
        for (int i = 0; i < 2; ++i) {
            int pbase = (w * 2 + i) * 1024;     // uniform slice base (bytes)
            int p = pbase + l * 16;
            int n = p >> 6, koff = (p & 63) >> 1;
            size_t src = (size_t)(ct * 128 + n) * 1024 + e0 + koff;
            gl_lds16(&Bhg[src], &Bh[pbase >> 1]);
            if (split) gl_lds16(&Blg[src], &Bl[pbase >> 1]);
        }
        __syncthreads();

        bfrag af[4], alf[4], bf_[4], blf[4];
        #pragma unroll
        for (int m = 0; m < 4; ++m) {
            int row = wm * 64 + m * 16 + (l & 15);
            af[m] = *(const bfrag*)&Ah[row * 32 + (l >> 4) * 8];
            if (split) alf[m] = *(const bfrag*)&Al[row * 32 + (l >> 4) * 8];
        }
        #pragma unroll
        for (int n = 0; n < 4; ++n) {
            int nr = wn * 64 + n * 16 + (l & 15);
            bf_[n] = *(const bfrag*)&Bh[nr * 32 + (l >> 4) * 8];
            if (split) blf[n] = *(const bfrag*)&Bl[nr * 32 + (l >> 4) * 8];
        }
        #pragma unroll
        for (int m = 0; m < 4; ++m)
            #pragma unroll
            for (int n = 0; n < 4; ++n) {
                acc[m][n] = MFMA(af[m], bf_[n], acc[m][n]);
                if (split) {
                    acc[m][n] = MFMA(af[m], blf[n], acc[m][n]);
                    acc[m][n] = MFMA(alf[m], bf_[n], acc[m][n]);
                }
            }
    }

    if (which == 2) {
        // v: write transposed vT[(h*2+b)*64 + d][t], pack 4 consecutive t (acc r=0..3)
        #pragma unroll
        for (int m = 0; m < 4; ++m) {
            int t0g = rt * 128 + wm * 64 + m * 16 + (l >> 4) * 4;  // x-row of r=0
            int b_ = t0g >> 11, t0 = t0g & 2047;
            #pragma unroll
            for (int n = 0; n < 4; ++n) {
                int col = ct * 128 + wn * 64 + n * 16 + (l & 15);
                int h_ = col >> 6, d = col & 63;
                us4 pk;
                #pragma unroll
                for (int r = 0; r < 4; ++r) pk[r] = f2bh(acc[m][n][r]);
                *(us4*)&vT[((size_t)((h_ * 2 + b_) * 64 + d)) * 2048 + t0] = pk;
            }
        }
    } else {
        unsigned short* oh = (which == 0) ? qh : kh;
        unsigned short* ol = (which == 0) ? ql : kl;
        const float sc = (which == 0) ? INV_SCALE : 1.0f;   // fold 1/sqrt(T) into Q
        #pragma unroll
        for (int m = 0; m < 4; ++m)
            #pragma unroll
            for (int r = 0; r < 4; ++r) {
                int row = rt * 128 + wm * 64 + m * 16 + (l >> 4) * 4 + r;
                #pragma unroll
                for (int n = 0; n < 4; ++n) {
                    int col = ct * 128 + wn * 64 + n * 16 + (l & 15);
                    float f = acc[m][n][r] * sc;
                    unsigned short hb = f2bh(f);
                    oh[(size_t)row * 1024 + col] = hb;
                    ol[(size_t)row * 1024 + col] = f2bh(f - bh2f(hb));
                }
            }
    }
}

// ---------------------------------------------------------------------------
// attn_mfma: flash attention.  grid (32 qt, 32 h*b), block 256 (4 waves).
// Wave w owns q-rows [qt*64+w*16, +16).  Q hi/lo frags hoisted to registers.
// K hi/lo and V^T tiles staged via global_load_lds with PRE-SWIZZLED source
// (XOR 16B-chunk swizzle) so ds_read_b128 at 128B row stride is conflict-free.
// QK^T = 3-term split MFMA; online softmax in 16-lane groups; P -> swizzled
// LDS (bf16) -> PV MFMA.
// ---------------------------------------------------------------------------
__global__ __launch_bounds__(256) void attn_mfma(
    const unsigned short* __restrict__ qh, const unsigned short* __restrict__ ql,
    const unsigned short* __restrict__ kh, const unsigned short* __restrict__ kl,
    const unsigned short* __restrict__ vT, unsigned short* __restrict__ att)
{
    __shared__ unsigned short Kh[64 * 64], Kl[64 * 64], Vt[64 * 64], Pl[64 * 64];
    const int tid = threadIdx.x, w = tid >> 6, l = tid & 63;
    const int qt = 31 - blockIdx.x;            // long blocks dispatch first
    const int hb = blockIdx.y, h = hb >> 1, b = hb & 1;

    // Q fragments (rows w*16+(l&15); k-chunks (l>>4)*8 within each 32-wide step)
    const int qrow = qt * 64 + w * 16 + (l & 15);
    const size_t qoff = (size_t)(b * 2048 + qrow) * 1024 + h * 64 + (l >> 4) * 8;
    bfrag qfh[2], qfl[2];
    qfh[0] = *(const bfrag*)&qh[qoff];
    qfh[1] = *(const bfrag*)&qh[qoff + 32];
    qfl[0] = *(const bfrag*)&ql[qoff];
    qfl[1] = *(const bfrag*)&ql[qoff + 32];

    facc O[4];
    float mrow[4], lrow[4], fac[4];
    #pragma unroll
    for (int f = 0; f < 4; ++f) O[f] = (facc)(0.0f);
    #pragma unroll
    for (int r = 0; r < 4; ++r) { mrow[r] = -1e30f; lrow[r] = 0.0f; }

    for (int kt = 0; kt <= qt; ++kt) {
        __syncthreads();   // previous iteration's LDS reads complete
        #pragma unroll
        for (int i = 0; i < 2; ++i) {
            int pbase = (w * 2 + i) * 1024;    // uniform 1KB slice base
            int p = pbase + l * 16;
            int row = p >> 7, slot = (p >> 4) & 7;
            int chunk = slot ^ (row & 7);      // inverse-swizzled source chunk
            size_t srcK = (size_t)(b * 2048 + kt * 64 + row) * 1024 + h * 64 + chunk * 8;
            size_t srcV = ((size_t)(h * 2 + b) * 64 + row) * 2048 + (size_t)kt * 64 + chunk * 8;
            gl_lds16(&kh[srcK], &Kh[pbase >> 1]);
            gl_lds16(&kl[srcK], &Kl[pbase >> 1]);
            gl_lds16(&vT[srcV], &Vt[pbase >> 1]);
        }
        __syncthreads();   // staging drained (compiler emits vmcnt(0) before barrier)

        // S = Q K^T  (split: qh*kh + qh*kl + ql*kh)
        facc S[4];
        #pragma unroll
        for (int f = 0; f < 4; ++f) S[f] = (facc)(0.0f);
        #pragma unroll
        for (int s = 0; s < 2; ++s) {
            #pragma unroll
            for (int f = 0; f < 4; ++f) {
                int key = f * 16 + (l & 15);
                int ch = (s * 4 + (l >> 4)) ^ (key & 7);
                bfrag kbh = *(const bfrag*)&Kh[key * 64 + ch * 8];
                bfrag kbl = *(const bfrag*)&Kl[key * 64 + ch * 8];
                S[f] = MFMA(qfh[s], kbh, S[f]);
                S[f] = MFMA(qfh[s], kbl, S[f]);
                S[f] = MFMA(qfl[s], kbh, S[f]);
            }
        }
        if (kt == qt) {    // causal mask on diagonal tile
            #pragma unroll
            for (int f = 0; f < 4; ++f) {
                int keyl = f * 16 + (l & 15);
                #pragma unroll
                for (int r = 0; r < 4; ++r) {
                    int qls = w * 16 + (l >> 4) * 4 + r;
                    if (keyl > qls) S[f][r] = -1e30f;
                }
            }
        }
        // online softmax; rows live in 16-lane groups (same l>>4)
        #pragma unroll
        for (int r = 0; r < 4; ++r) {
            float mx = fmaxf(fmaxf(S[0][r], S[1][r]), fmaxf(S[2][r], S[3][r]));
            mx = fmaxf(mx, __shfl_xor(mx, 1));
            mx = fmaxf(mx, __shfl_xor(mx, 2));
            mx = fmaxf(mx, __shfl_xor(mx, 4));
            mx = fmaxf(mx, __shfl_xor(mx, 8));
            float mn = fmaxf(mrow[r], mx);
            fac[r] = __expf(mrow[r] - mn);
            mrow[r] = mn;
            float rs = 0.0f;
            #pragma unroll
            for (int f = 0; f < 4; ++f) { S[f][r] = __expf(S[f][r] - mn); rs += S[f][r]; }
            rs += __shfl_xor(rs, 1); rs += __shfl_xor(rs, 2);
            rs += __shfl_xor(rs, 4); rs += __shfl_xor(rs, 8);
            lrow[r] = lrow[r] * fac[r] + rs;
            #pragma unroll
            for (int f = 0; f < 4; ++f) O[f][r] *= fac[r];
        }
        // P -> LDS (bf16, swizzled rows)
        #pragma unroll
        for (int f = 0; f < 4; ++f) {
            int key = f * 16 + (l & 15);
            #pragma unroll
            for (int r = 0; r < 4; ++r) {
                int qr = w * 16 + (l >> 4) * 4 + r;
                Pl[qr * 64 + (((key >> 3) ^ (qr & 7)) * 8) + (key & 7)] = f2bh(S[f][r]);
            }
        }
        __syncthreads();   // P visible to all lanes
        // O += P V
        #pragma unroll
        for (int s = 0; s < 2; ++s) {
            int qa = w * 16 + (l & 15);
            int cha = (s * 4 + (l >> 4)) ^ (qa & 7);
            bfrag pa = *(const bfrag*)&Pl[qa * 64 + cha * 8];
            #pragma unroll
            for (int f = 0; f < 4; ++f) {
                int d = f * 16 + (l & 15);
                int chv = (s * 4 + (l >> 4)) ^ (d & 7);
                bfrag vb = *(const bfrag*)&Vt[d * 64 + chv * 8];
                O[f] = MFMA(pa, vb, O[f]);
            }
        }
    }
    // epilogue: att[b*2048+t][h*64+d] = O/l  (bf16)
    #pragma unroll
    for (int f = 0; f < 4; ++f) {
        int d = h * 64 + f * 16 + (l & 15);
        #pragma unroll
        for (int r = 0; r < 4; ++r) {
            int t = qt * 64 + w * 16 + (l >> 4) * 4 + r;
            att[(size_t)(b * 2048 + t) * 1024 + d] = f2bh(O[f][r] / lrow[r]);
        }
    }
}

// ---------------------------------------------------------------------------
// outproj: out[4096,1024] = att @ Wo^T, bf16 MFMA, fp32 out.  grid (32, 8).
// ---------------------------------------------------------------------------
__global__ __launch_bounds__(256) void outproj(
    const unsigned short* __restrict__ att, const unsigned short* __restrict__ WoB,
    float* __restrict__ out)
{
    __shared__ unsigned short Ab[128 * 32], Bb[128 * 32];
    const int tid = threadIdx.x, w = tid >> 6, l = tid & 63;
    const int wm = w >> 1, wn = w & 1;
    const int rt = blockIdx.x, ct = blockIdx.y;

    facc acc[4][4];
    #pragma unroll
    for (int i = 0; i < 4; ++i)
        #pragma unroll
        for (int j = 0; j < 4; ++j) acc[i][j] = (facc)(0.0f);

    for (int e0 = 0; e0 < 1024; e0 += 32) {
        __syncthreads();
        #pragma unroll
        for (int i = 0; i < 2; ++i) {
            int pbase = (w * 2 + i) * 1024;
            int p = pbase + l * 16;
            int row = p >> 6, koff = (p & 63) >> 1;
            gl_lds16(&att[(size_t)(rt * 128 + row) * 1024 + e0 + koff], &Ab[pbase >> 1]);
            gl_lds16(&WoB[(size_t)(ct * 128 + row) * 1024 + e0 + koff], &Bb[pbase >> 1]);
        }
        __syncthreads();
        bfrag af[4], bf_[4];
        #pragma unroll
        for (int m = 0; m < 4; ++m)
            af[m] = *(const bfrag*)&Ab[(wm * 64 + m * 16 + (l & 15)) * 32 + (l >> 4) * 8];
        #pragma unroll
        for (int n = 0; n < 4; ++n)
            bf_[n] = *(const bfrag*)&Bb[(wn * 64 + n * 16 + (l & 15)) * 32 + (l >> 4) * 8];
        #pragma unroll
        for (int m = 0; m < 4; ++m)
            #pragma unroll
            for (int n = 0; n < 4; ++n)
                acc[m][n] = MFMA(af[m], bf_[n], acc[m][n]);
    }
    #pragma unroll
    for (int m = 0; m < 4; ++m)
        #pragma unroll
        for (int r = 0; r < 4; ++r) {
            int row = rt * 128 + wm * 64 + m * 16 + (l >> 4) * 4 + r;
            #pragma unroll
            for (int n = 0; n < 4; ++n) {
                int col = ct * 128 + wn * 64 + n * 16 + (l & 15);
                out[(size_t)row * 1024 + col] = acc[m][n][r];
            }
        }
}

// ---------------------------------------------------------------------------
extern "C" void kernel_launch(void* const* d_in, const int* in_sizes, int n_in,
                              void* d_out, int out_size, void* d_ws, size_t ws_size,
                              hipStream_t stream) {
    const float* x  = (const float*)d_in[0];
    // d_in[1]: causal mask (applied analytically)
    const float* Wq = (const float*)d_in[2];
    const float* Wk = (const float*)d_in[3];
    const float* Wv = (const float*)d_in[4];
    const float* Wo = (const float*)d_in[5];

    uint8_t* wsb = (uint8_t*)d_ws;
    const size_t MB = 1024 * 1024;
    unsigned short* WqTh = (unsigned short*)(wsb + 0 * MB);   // [1024 n][1024 e] bf16
    unsigned short* WqTl = (unsigned short*)(wsb + 2 * MB);
    unsigned short* WkTh = (unsigned short*)(wsb + 4 * MB);
    unsigned short* WkTl = (unsigned short*)(wsb + 6 * MB);
    unsigned short* WvT  = (unsigned short*)(wsb + 8 * MB);
    unsigned short* WoB  = (unsigned short*)(wsb + 10 * MB);  // [1024 o][1024 i] bf16
    unsigned short* qh   = (unsigned short*)(wsb + 12 * MB);  // [4096][1024] bf16
    unsigned short* ql   = (unsigned short*)(wsb + 20 * MB);
    unsigned short* kh   = (unsigned short*)(wsb + 28 * MB);
    unsigned short* kl   = (unsigned short*)(wsb + 36 * MB);
    unsigned short* vT   = (unsigned short*)(wsb + 44 * MB);  // [2048 hd][2048 t] bf16
    unsigned short* att  = (unsigned short*)(wsb + 52 * MB);  // [4096][1024] bf16

    prep_w<<<dim3(16, 16, 3), 256, 0, stream>>>(Wq, Wk, Wv, WqTh, WqTl, WkTh, WkTl, WvT);
    wo_conv<<<dim3(1024), 256, 0, stream>>>(Wo, WoB);
    qkv_gemm<<<dim3(32, 8, 3), 256, 0, stream>>>(x, WqTh, WqTl, WkTh, WkTl, WvT,
                                                 qh, ql, kh, kl, vT);
    attn_mfma<<<dim3(32, 32), 256, 0, stream>>>(qh, ql, kh, kl, vT, att);
    outproj<<<dim3(32, 8), 256, 0, stream>>>(att, WoB, (float*)d_out);
}

// Round 4
// 202.353 us; speedup vs baseline: 9.8762x; 1.3443x over previous
//
#include <hip/hip_runtime.h>
#include <stdint.h>

// (B,T,E,H,D) = (2,2048,1024,16,64)
constexpr float INV_SCALE = 0.022097086912079608f;  // 1/sqrt(2048)
constexpr float LOG2E = 1.4426950408889634f;
constexpr float QSC = INV_SCALE * LOG2E;            // q pre-scale: softmax in exp2 domain

typedef __attribute__((ext_vector_type(8))) short bfrag;          // 8 bf16 (4 VGPR) MFMA frag
typedef __attribute__((ext_vector_type(4))) float facc;           // 4 f32 MFMA acc
typedef __attribute__((ext_vector_type(4))) unsigned short us4;   // 4 bf16 = 8B

#define MFMA(a, b, c) __builtin_amdgcn_mfma_f32_16x16x32_bf16((a), (b), (c), 0, 0, 0)
#define EXP2(x) __builtin_amdgcn_exp2f(x)

__device__ __forceinline__ unsigned short f2bh(float f) {        // f32 -> bf16 RNE
    union { float f; unsigned int u; } cv; cv.f = f;
    unsigned int u = cv.u;
    u += 0x7FFFu + ((u >> 16) & 1u);
    return (unsigned short)(u >> 16);
}
__device__ __forceinline__ float bh2f(unsigned short h) {
    union { unsigned int u; float f; } cv; cv.u = ((unsigned int)h) << 16;
    return cv.f;
}
__device__ __forceinline__ void gl_lds16(const unsigned short* g, unsigned short* lds) {
    // async 16B/lane global->LDS; dst is wave-uniform base, lane i lands at dst+16*i
    __builtin_amdgcn_global_load_lds(
        (const __attribute__((address_space(1))) unsigned int*)g,
        (__attribute__((address_space(3))) unsigned int*)lds, 16, 0, 0);
}

// ---------------------------------------------------------------------------
// prep_w: per head, transpose W[h][1024 e][64 i] -> WT[h*64+i][1024 e] with
// hi/lo bf16 split for Wq/Wk (Q/K path needs ~fp32 logits), hi-only for Wv.
// grid (16 etiles, 16 heads, 3), block 256.
// ---------------------------------------------------------------------------
__global__ __launch_bounds__(256) void prep_w(
    const float* __restrict__ Wq, const float* __restrict__ Wk, const float* __restrict__ Wv,
    unsigned short* __restrict__ WqTh, unsigned short* __restrict__ WqTl,
    unsigned short* __restrict__ WkTh, unsigned short* __restrict__ WkTl,
    unsigned short* __restrict__ WvT)
{
    __shared__ float tile[64][65];
    const int tid = threadIdx.x;
    const int et = blockIdx.x, h = blockIdx.y, m = blockIdx.z;
    const float* W = (m == 0) ? Wq : (m == 1) ? Wk : Wv;
    #pragma unroll
    for (int rep = 0; rep < 4; ++rep) {
        int idx = rep * 256 + tid;            // f4 idx over [64e][16 i4]
        int e = idx >> 4, i4 = (idx & 15) * 4;
        facc v = *(const facc*)&W[(size_t)h * 65536 + (size_t)(et * 64 + e) * 64 + i4];
        tile[e][i4] = v.x; tile[e][i4 + 1] = v.y; tile[e][i4 + 2] = v.z; tile[e][i4 + 3] = v.w;
    }
    __syncthreads();
    unsigned short* Oh = (m == 0) ? WqTh : (m == 1) ? WkTh : WvT;
    unsigned short* Ol = (m == 0) ? WqTl : WkTl;   // unused when m==2
    #pragma unroll
    for (int rep = 0; rep < 4; ++rep) {
        int idx = rep * 256 + tid;            // [64 i][16 e4]
        int i = idx >> 4, e4 = (idx & 15) * 4;
        us4 hv, lv;
        #pragma unroll
        for (int j = 0; j < 4; ++j) {
            float f = tile[e4 + j][i];
            unsigned short hb = f2bh(f);
            hv[j] = hb;
            lv[j] = f2bh(f - bh2f(hb));
        }
        size_t o = (size_t)(h * 64 + i) * 1024 + et * 64 + e4;
        *(us4*)&Oh[o] = hv;
        if (m < 2) *(us4*)&Ol[o] = lv;
    }
}

// Wo [1024 o][1024 i] fp32 -> bf16 (already B^T layout for out = att @ Wo^T)
__global__ __launch_bounds__(256) void wo_conv(const float* __restrict__ Wo,
                                               unsigned short* __restrict__ WoB) {
    int idx = blockIdx.x * 256 + threadIdx.x;   // f4 index, 262144 total
    facc v = *(const facc*)&Wo[(size_t)idx * 4];
    us4 o;
    #pragma unroll
    for (int j = 0; j < 4; ++j) o[j] = f2bh(v[j]);
    *(us4*)&WoB[(size_t)idx * 4] = o;
}

// ---------------------------------------------------------------------------
// qkv_gemm: C[4096,1024] = X @ W  per which in {q,k,v}.  128x128 tile, BK=32,
// 4 waves each 64x64 (4x4 frags).  A staged from fp32 with in-kernel hi/lo
// split; B via global_load_lds from pre-split planes.  q/k: 3-term split MFMA.
// Epilogue: q,k -> hi/lo planes (q pre-scaled by 1/sqrt(T)*log2(e)); v -> vT.
// grid (32, 8, 3), block 256.
// ---------------------------------------------------------------------------
__global__ __launch_bounds__(256) void qkv_gemm(
    const float* __restrict__ x,
    const unsigned short* __restrict__ WqTh, const unsigned short* __restrict__ WqTl,
    const unsigned short* __restrict__ WkTh, const unsigned short* __restrict__ WkTl,
    const unsigned short* __restrict__ WvT,
    unsigned short* __restrict__ qh, unsigned short* __restrict__ ql,
    unsigned short* __restrict__ kh, unsigned short* __restrict__ kl,
    unsigned short* __restrict__ vT)
{
    __shared__ unsigned short Ah[128 * 32], Al[128 * 32], Bh[128 * 32], Bl[128 * 32];
    const int tid = threadIdx.x;
    const int w = tid >> 6, l = tid & 63;
    const int wm = w >> 1, wn = w & 1;
    const int rt = blockIdx.x, ct = blockIdx.y, which = blockIdx.z;
    const bool split = (which < 2);
    const unsigned short* Bhg = (which == 0) ? WqTh : (which == 1) ? WkTh : WvT;
    const unsigned short* Blg = (which == 0) ? WqTl : WkTl;

    facc acc[4][4];
    #pragma unroll
    for (int i = 0; i < 4; ++i)
        #pragma unroll
        for (int j = 0; j < 4; ++j) acc[i][j] = (facc)(0.0f);

    for (int e0 = 0; e0 < 1024; e0 += 32) {
        __syncthreads();
        // stage A: 128x32 fp32 -> bf16 hi/lo
        #pragma unroll
        for (int rep = 0; rep < 4; ++rep) {
            int idx = rep * 256 + tid;          // f4 idx, 1024 total
            int row = idx >> 3, c4 = (idx & 7) * 4;
            facc xv = *(const facc*)&x[(size_t)(rt * 128 + row) * 1024 + e0 + c4];
            us4 hv, lv;
            #pragma unroll
            for (int j = 0; j < 4; ++j) {
                float f = xv[j];
                unsigned short hb = f2bh(f);
                hv[j] = hb;
                lv[j] = f2bh(f - bh2f(hb));
            }
            *(us4*)&Ah[row * 32 + c4] = hv;
            if (split) *(us4*)&Al[row * 32 + c4] = lv;
        }
        // stage B (8KB/plane, 8 x 1KB wave-slices)
        #pragma unroll
        for (int i = 0; i < 2; ++i) {
            int pbase = (w * 2 + i) * 1024;     // uniform slice base (bytes)
            int p = pbase + l * 16;
            int n = p >> 6, koff = (p & 63) >> 1;
            size_t src = (size_t)(ct * 128 + n) * 1024 + e0 + koff;
            gl_lds16(&Bhg[src], &Bh[pbase >> 1]);
            if (split) gl_lds16(&Blg[src], &Bl[pbase >> 1]);
        }
        __syncthreads();

        bfrag af[4], alf[4], bf_[4], blf[4];
        #pragma unroll
        for (int m = 0; m < 4; ++m) {
            int row = wm * 64 + m * 16 + (l & 15);
            af[m] = *(const bfrag*)&Ah[row * 32 + (l >> 4) * 8];
            if (split) alf[m] = *(const bfrag*)&Al[row * 32 + (l >> 4) * 8];
        }
        #pragma unroll
        for (int n = 0; n < 4; ++n) {
            int nr = wn * 64 + n * 16 + (l & 15);
            bf_[n] = *(const bfrag*)&Bh[nr * 32 + (l >> 4) * 8];
            if (split) blf[n] = *(const bfrag*)&Bl[nr * 32 + (l >> 4) * 8];
        }
        #pragma unroll
        for (int m = 0; m < 4; ++m)
            #pragma unroll
            for (int n = 0; n < 4; ++n) {
                acc[m][n] = MFMA(af[m], bf_[n], acc[m][n]);
                if (split) {
                    acc[m][n] = MFMA(af[m], blf[n], acc[m][n]);
                    acc[m][n] = MFMA(alf[m], bf_[n], acc[m][n]);
                }
            }
    }

    if (which == 2) {
        // v: write transposed vT[(h*2+b)*64 + d][t], pack 4 consecutive t (acc r=0..3)
        #pragma unroll
        for (int m = 0; m < 4; ++m) {
            int t0g = rt * 128 + wm * 64 + m * 16 + (l >> 4) * 4;  // x-row of r=0
            int b_ = t0g >> 11, t0 = t0g & 2047;
            #pragma unroll
            for (int n = 0; n < 4; ++n) {
                int col = ct * 128 + wn * 64 + n * 16 + (l & 15);
                int h_ = col >> 6, d = col & 63;
                us4 pk;
                #pragma unroll
                for (int r = 0; r < 4; ++r) pk[r] = f2bh(acc[m][n][r]);
                *(us4*)&vT[((size_t)((h_ * 2 + b_) * 64 + d)) * 2048 + t0] = pk;
            }
        }
    } else {
        unsigned short* oh = (which == 0) ? qh : kh;
        unsigned short* ol = (which == 0) ? ql : kl;
        const float sc = (which == 0) ? QSC : 1.0f;
        #pragma unroll
        for (int m = 0; m < 4; ++m)
            #pragma unroll
            for (int r = 0; r < 4; ++r) {
                int row = rt * 128 + wm * 64 + m * 16 + (l >> 4) * 4 + r;
                #pragma unroll
                for (int n = 0; n < 4; ++n) {
                    int col = ct * 128 + wn * 64 + n * 16 + (l & 15);
                    float f = acc[m][n][r] * sc;
                    unsigned short hb = f2bh(f);
                    oh[(size_t)row * 1024 + col] = hb;
                    ol[(size_t)row * 1024 + col] = f2bh(f - bh2f(hb));
                }
            }
    }
}

// ---------------------------------------------------------------------------
// attn helpers
// ---------------------------------------------------------------------------
__device__ __forceinline__ void stage_kv(
    const unsigned short* __restrict__ kh, const unsigned short* __restrict__ kl,
    const unsigned short* __restrict__ vT,
    unsigned short* Khb, unsigned short* Klb, unsigned short* Vtb,
    int w, int l, int b, int h, int kt)
{
    #pragma unroll
    for (int i = 0; i < 2; ++i) {
        int pbase = (w * 2 + i) * 1024;    // uniform 1KB slice base (bytes)
        int p = pbase + l * 16;
        int row = p >> 7, slot = (p >> 4) & 7;
        int chunk = slot ^ (row & 7);      // inverse-swizzled source chunk
        size_t srcK = (size_t)(b * 2048 + kt * 64 + row) * 1024 + h * 64 + chunk * 8;
        size_t srcV = ((size_t)(h * 2 + b) * 64 + row) * 2048 + (size_t)kt * 64 + chunk * 8;
        gl_lds16(&kh[srcK], &Khb[pbase >> 1]);
        gl_lds16(&kl[srcK], &Klb[pbase >> 1]);
        gl_lds16(&vT[srcV], &Vtb[pbase >> 1]);
    }
}

// One 64-key flash step for one q-tile's state (split QK^T, exp2 softmax, PV).
__device__ __forceinline__ void attn_step(
    const unsigned short* Khb, const unsigned short* Klb, const unsigned short* Vtb,
    unsigned short* Pl, const bfrag* qfh, const bfrag* qfl,
    facc* O, float* mrow, float* lrow, int w, int l, bool diag)
{
    facc S[4];
    #pragma unroll
    for (int f = 0; f < 4; ++f) S[f] = (facc)(0.0f);
    #pragma unroll
    for (int s = 0; s < 2; ++s) {
        #pragma unroll
        for (int f = 0; f < 4; ++f) {
            int key = f * 16 + (l & 15);
            int ch = (s * 4 + (l >> 4)) ^ (key & 7);
            bfrag kbh = *(const bfrag*)&Khb[key * 64 + ch * 8];
            bfrag kbl = *(const bfrag*)&Klb[key * 64 + ch * 8];
            S[f] = MFMA(qfh[s], kbh, S[f]);
            S[f] = MFMA(qfh[s], kbl, S[f]);
            S[f] = MFMA(qfl[s], kbh, S[f]);
        }
    }
    if (diag) {
        #pragma unroll
        for (int f = 0; f < 4; ++f) {
            int keyl = f * 16 + (l & 15);
            #pragma unroll
            for (int r = 0; r < 4; ++r) {
                int qls = w * 16 + (l >> 4) * 4 + r;
                if (keyl > qls) S[f][r] = -1e30f;
            }
        }
    }
    #pragma unroll
    for (int r = 0; r < 4; ++r) {
        float mx = fmaxf(fmaxf(S[0][r], S[1][r]), fmaxf(S[2][r], S[3][r]));
        mx = fmaxf(mx, __shfl_xor(mx, 1));
        mx = fmaxf(mx, __shfl_xor(mx, 2));
        mx = fmaxf(mx, __shfl_xor(mx, 4));
        mx = fmaxf(mx, __shfl_xor(mx, 8));
        float mn = fmaxf(mrow[r], mx);
        float fac = EXP2(mrow[r] - mn);   // exp2 domain (q pre-scaled by log2e)
        mrow[r] = mn;
        float rs = 0.0f;
        #pragma unroll
        for (int f = 0; f < 4; ++f) { S[f][r] = EXP2(S[f][r] - mn); rs += S[f][r]; }
        rs += __shfl_xor(rs, 1); rs += __shfl_xor(rs, 2);
        rs += __shfl_xor(rs, 4); rs += __shfl_xor(rs, 8);
        lrow[r] = lrow[r] * fac + rs;
        O[0][r] *= fac; O[1][r] *= fac; O[2][r] *= fac; O[3][r] *= fac;
    }
    // P -> LDS (bf16, swizzled rows); each wave touches only its own 16 rows,
    // so no barrier needed -- same-wave ds ordering is handled by lgkmcnt.
    #pragma unroll
    for (int f = 0; f < 4; ++f) {
        int key = f * 16 + (l & 15);
        #pragma unroll
        for (int r = 0; r < 4; ++r) {
            int qr = w * 16 + (l >> 4) * 4 + r;
            Pl[qr * 64 + (((key >> 3) ^ (qr & 7)) * 8) + (key & 7)] = f2bh(S[f][r]);
        }
    }
    #pragma unroll
    for (int s = 0; s < 2; ++s) {
        int qa = w * 16 + (l & 15);
        int cha = (s * 4 + (l >> 4)) ^ (qa & 7);
        bfrag pa = *(const bfrag*)&Pl[qa * 64 + cha * 8];
        #pragma unroll
        for (int f = 0; f < 4; ++f) {
            int d = f * 16 + (l & 15);
            int chv = (s * 4 + (l >> 4)) ^ (d & 7);
            bfrag vb = *(const bfrag*)&Vtb[d * 64 + chv * 8];
            O[f] = MFMA(pa, vb, O[f]);
        }
    }
}

// ---------------------------------------------------------------------------
// attn_mfma: paired-q-tile flash attention.  grid (16, 32), block 256 (4 waves).
// Block (bx,hb) handles q-tiles {31-bx, bx}: uniform 33 steps per block.
// K/V double-buffered; prefetch stays in flight across a RAW s_barrier
// (counted-drain happens at the next __syncthreads).  2 blocks/CU exactly.
// ---------------------------------------------------------------------------
__global__ __launch_bounds__(256, 2) void attn_mfma(
    const unsigned short* __restrict__ qh, const unsigned short* __restrict__ ql,
    const unsigned short* __restrict__ kh, const unsigned short* __restrict__ kl,
    const unsigned short* __restrict__ vT, unsigned short* __restrict__ att)
{
    __shared__ unsigned short Kh[2][64 * 64], Kl[2][64 * 64], Vt[2][64 * 64], Pl[64 * 64];
    const int tid = threadIdx.x, w = tid >> 6, l = tid & 63;
    // XCD-grouping swizzle (assumes round-robin dispatch over 8 XCDs):
    // all 16 q-blocks of 4 consecutive hb land on one XCD -> K/V L2-resident.
    const int dd = blockIdx.y * 16 + blockIdx.x;
    const int xcd = dd & 7, sl = dd >> 3;
    const int hb = xcd * 4 + (sl >> 4);
    const int bx = sl & 15;
    const int qtA = 31 - bx, qtB = bx;
    const int h = hb >> 1, b = hb & 1;

    bfrag qfhA[2], qflA[2], qfhB[2], qflB[2];
    {
        const int qrowA = qtA * 64 + w * 16 + (l & 15);
        const size_t qoffA = (size_t)(b * 2048 + qrowA) * 1024 + h * 64 + (l >> 4) * 8;
        qfhA[0] = *(const bfrag*)&qh[qoffA];
        qfhA[1] = *(const bfrag*)&qh[qoffA + 32];
        qflA[0] = *(const bfrag*)&ql[qoffA];
        qflA[1] = *(const bfrag*)&ql[qoffA + 32];
        const int qrowB = qtB * 64 + w * 16 + (l & 15);
        const size_t qoffB = (size_t)(b * 2048 + qrowB) * 1024 + h * 64 + (l >> 4) * 8;
        qfhB[0] = *(const bfrag*)&qh[qoffB];
        qfhB[1] = *(const bfrag*)&qh[qoffB + 32];
        qflB[0] = *(const bfrag*)&ql[qoffB];
        qflB[1] = *(const bfrag*)&ql[qoffB + 32];
    }

    facc OA[4], OB[4];
    float mA[4], lA[4], mB[4], lB[4];
    #pragma unroll
    for (int f = 0; f < 4; ++f) { OA[f] = (facc)(0.0f); OB[f] = (facc)(0.0f); }
    #pragma unroll
    for (int r = 0; r < 4; ++r) { mA[r] = -1e30f; lA[r] = 0.0f; mB[r] = -1e30f; lB[r] = 0.0f; }

    stage_kv(kh, kl, vT, Kh[0], Kl[0], Vt[0], w, l, b, h, 0);
    int cur = 0;
    for (int kt = 0; kt <= qtA; ++kt) {
        // A: drains my previous stage (landed during prior compute) and makes
        // buf[cur^1] WAR-safe for the prefetch below.
        __syncthreads();
        if (kt < qtA)
            stage_kv(kh, kl, vT, Kh[cur ^ 1], Kl[cur ^ 1], Vt[cur ^ 1], w, l, b, h, kt + 1);
        __builtin_amdgcn_sched_barrier(0);
        // B: raw barrier, NO vmcnt -- the 6 prefetch loads stay in flight.
        // buf[cur] is complete because every wave drained it at its own A.
        __builtin_amdgcn_s_barrier();
        __builtin_amdgcn_sched_barrier(0);
        attn_step(Kh[cur], Kl[cur], Vt[cur], Pl, qfhA, qflA, OA, mA, lA, w, l, kt == qtA);
        if (kt <= qtB)
            attn_step(Kh[cur], Kl[cur], Vt[cur], Pl, qfhB, qflB, OB, mB, lB, w, l, kt == qtB);
        cur ^= 1;
    }

    #pragma unroll
    for (int f = 0; f < 4; ++f) {
        int d = h * 64 + f * 16 + (l & 15);
        #pragma unroll
        for (int r = 0; r < 4; ++r) {
            int tA = qtA * 64 + w * 16 + (l >> 4) * 4 + r;
            att[(size_t)(b * 2048 + tA) * 1024 + d] = f2bh(OA[f][r] / lA[r]);
            int tB = qtB * 64 + w * 16 + (l >> 4) * 4 + r;
            att[(size_t)(b * 2048 + tB) * 1024 + d] = f2bh(OB[f][r] / lB[r]);
        }
    }
}

// ---------------------------------------------------------------------------
// outproj: out[4096,1024] = att @ Wo^T, bf16 MFMA, fp32 out.  grid (32, 8).
// ---------------------------------------------------------------------------
__global__ __launch_bounds__(256) void outproj(
    const unsigned short* __restrict__ att, const unsigned short* __restrict__ WoB,
    float* __restrict__ out)
{
    __shared__ unsigned short Ab[128 * 32], Bb[128 * 32];
    const int tid = threadIdx.x, w = tid >> 6, l = tid & 63;
    const int wm = w >> 1, wn = w & 1;
    const int rt = blockIdx.x, ct = blockIdx.y;

    facc acc[4][4];
    #pragma unroll
    for (int i = 0; i < 4; ++i)
        #pragma unroll
        for (int j = 0; j < 4; ++j) acc[i][j] = (facc)(0.0f);

    for (int e0 = 0; e0 < 1024; e0 += 32) {
        __syncthreads();
        #pragma unroll
        for (int i = 0; i < 2; ++i) {
            int pbase = (w * 2 + i) * 1024;
            int p = pbase + l * 16;
            int row = p >> 6, koff = (p & 63) >> 1;
            gl_lds16(&att[(size_t)(rt * 128 + row) * 1024 + e0 + koff], &Ab[pbase >> 1]);
            gl_lds16(&WoB[(size_t)(ct * 128 + row) * 1024 + e0 + koff], &Bb[pbase >> 1]);
        }
        __syncthreads();
        bfrag af[4], bf_[4];
        #pragma unroll
        for (int m = 0; m < 4; ++m)
            af[m] = *(const bfrag*)&Ab[(wm * 64 + m * 16 + (l & 15)) * 32 + (l >> 4) * 8];
        #pragma unroll
        for (int n = 0; n < 4; ++n)
            bf_[n] = *(const bfrag*)&Bb[(wn * 64 + n * 16 + (l & 15)) * 32 + (l >> 4) * 8];
        #pragma unroll
        for (int m = 0; m < 4; ++m)
            #pragma unroll
            for (int n = 0; n < 4; ++n)
                acc[m][n] = MFMA(af[m], bf_[n], acc[m][n]);
    }
    #pragma unroll
    for (int m = 0; m < 4; ++m)
        #pragma unroll
        for (int r = 0; r < 4; ++r) {
            int row = rt * 128 + wm * 64 + m * 16 + (l >> 4) * 4 + r;
            #pragma unroll
            for (int n = 0; n < 4; ++n) {
                int col = ct * 128 + wn * 64 + n * 16 + (l & 15);
                out[(size_t)row * 1024 + col] = acc[m][n][r];
            }
        }
}

// ---------------------------------------------------------------------------
extern "C" void kernel_launch(void* const* d_in, const int* in_sizes, int n_in,
                              void* d_out, int out_size, void* d_ws, size_t ws_size,
                              hipStream_t stream) {
    const float* x  = (const float*)d_in[0];
    // d_in[1]: causal mask (applied analytically)
    const float* Wq = (const float*)d_in[2];
    const float* Wk = (const float*)d_in[3];
    const float* Wv = (const float*)d_in[4];
    const float* Wo = (const float*)d_in[5];

    uint8_t* wsb = (uint8_t*)d_ws;
    const size_t MB = 1024 * 1024;
    unsigned short* WqTh = (unsigned short*)(wsb + 0 * MB);   // [1024 n][1024 e] bf16
    unsigned short* WqTl = (unsigned short*)(wsb + 2 * MB);
    unsigned short* WkTh = (unsigned short*)(wsb + 4 * MB);
    unsigned short* WkTl = (unsigned short*)(wsb + 6 * MB);
    unsigned short* WvT  = (unsigned short*)(wsb + 8 * MB);
    unsigned short* WoB  = (unsigned short*)(wsb + 10 * MB);  // [1024 o][1024 i] bf16
    unsigned short* qh   = (unsigned short*)(wsb + 12 * MB);  // [4096][1024] bf16
    unsigned short* ql   = (unsigned short*)(wsb + 20 * MB);
    unsigned short* kh   = (unsigned short*)(wsb + 28 * MB);
    unsigned short* kl   = (unsigned short*)(wsb + 36 * MB);
    unsigned short* vT   = (unsigned short*)(wsb + 44 * MB);  // [2048 hd][2048 t] bf16
    unsigned short* att  = (unsigned short*)(wsb + 52 * MB);  // [4096][1024] bf16

    prep_w<<<dim3(16, 16, 3), 256, 0, stream>>>(Wq, Wk, Wv, WqTh, WqTl, WkTh, WkTl, WvT);
    wo_conv<<<dim3(1024), 256, 0, stream>>>(Wo, WoB);
    qkv_gemm<<<dim3(32, 8, 3), 256, 0, stream>>>(x, WqTh, WqTl, WkTh, WkTl, WvT,
                                                 qh, ql, kh, kl, vT);
    attn_mfma<<<dim3(16, 32), 256, 0, stream>>>(qh, ql, kh, kl, vT, att);
    outproj<<<dim3(32, 8), 256, 0, stream>>>(att, WoB, (float*)d_out);
}